// Round 15
// baseline (87.500 us; speedup 1.0000x reference)
//
#include <hip/hip_runtime.h>
#include <stdint.h>

#define T_STEPS 256
#define H1 5
#define H2 100
#define NSTR 16     // batch streams per block (MFMA N dim)
#define MT 7        // M tiles: 112 rows = 100 h2 + 5 h1 + 7 pad
#define KT 4        // K tiles: 128 cols = 100 h2 + 5 h1 + bias + x + 21 pad
#define ME 112
#define KE 128
#define XPAD 260    // xs row stride (floats)
#define NW 4        // waves: w0..w2 own 2 M-tiles each, w3 owns tile 6 + inject
#define NTHR (NW * 64)

typedef _Float16 f16;
typedef _Float16 half8 __attribute__((ext_vector_type(8)));
typedef _Float16 f16x2 __attribute__((ext_vector_type(2)));
typedef float    floatx4 __attribute__((ext_vector_type(4)));

// State buffer layout (per buffer, 2048 f16 = 4 KB):
//   16B chunk (kt, g, n) at byte offset kt*1024 + g*256 + n*16
//   holds k-rows 32kt+8g .. +7 of stream n.
// B-read for lane l=(g*16+n): addr = lane*16 + kt*1024  -> perfectly linear.
// f16 index of (k, n): ((k>>5)<<9) + (((k>>3)&3)<<7) + (n<<3) + (k&7)
__device__ __forceinline__ int sidx(int k, int n) {
    return ((k >> 5) << 9) + (((k >> 3) & 3) << 7) + (n << 3) + (k & 7);
}

// tanh(x) = 1 - 2/(exp(2x)+1); saturates correctly for |x| large.
__device__ __forceinline__ float fast_tanh(float v) {
    float e = __expf(2.0f * v);
    return 1.0f - 2.0f * __builtin_amdgcn_rcpf(e + 1.0f);
}

// pack two f32 -> u32 of two f16 (RTE)
__device__ __forceinline__ uint32_t pkf16(float a, float b) {
    f16x2 v; v.x = (f16)a; v.y = (f16)b;
    return __builtin_bit_cast(uint32_t, v);
}

#define MFMA(Aa, Bb, Dd) __builtin_amdgcn_mfma_f32_16x16x32_f16((Aa), (Bb), (Dd), 0, 0, 0)

// 4 waves per block (1 per SIMD), 16 batch streams. Waves 0..2 own two
// 16-row M-tiles each (one shared B-read feeds 8 MFMAs -> LDS traffic
// halves vs 7-wave split); wave 3 owns tile 6 + the x-injection.
// Full 2-layer RNN step = one 112x128 fp16 matrix-vector recurrence:
//   A rows 0..99:   [Whh2 | Wih2 | bias2 | 0...]      -> h2_t
//   A rows 100..104:[  0  | Whh1 | bias1 | Wih1 | 0]  -> h1_{t+1}
// State double-buffered in LDS in B-fragment order (sidx): linear reads,
// bank-tiled writes, one barrier per step. Constants (row 105 = 1.0,
// rows 107..127 = 0) are written once at init.
__global__ __launch_bounds__(NTHR, 1) void rnn_mfma4w(
    const float* __restrict__ x,
    const float* __restrict__ Wih1, const float* __restrict__ Whh1,
    const float* __restrict__ bih1, const float* __restrict__ bhh1,
    const float* __restrict__ Wih2, const float* __restrict__ Whh2,
    const float* __restrict__ bih2, const float* __restrict__ bhh2,
    const float* __restrict__ W3,   const float* __restrict__ b3,
    float* __restrict__ out)
{
    const int tid  = threadIdx.x;        // 0..255
    const int lane = tid & 63;
    const int wid  = tid >> 6;           // 0..3
    const int n    = lane & 15;          // stream / D-col
    const int g    = lane >> 4;          // k-group / D-row-group
    const int bbase = blockIdx.x * NSTR;

    __shared__ __align__(16) f16   Wlds[ME][KE];     // 28 KB extended matrix
    __shared__ __align__(16) float xs[NSTR][XPAD];   // 16.6 KB x rows
    __shared__ __align__(16) f16   st[2][2048];      // 8 KB state (dbuf)
    __shared__ float pp[NW][NSTR];                   // epilogue partials

    // ---- zero Wlds (7168 u32 = 256*28) + preload x (1024 float4) ----
    {
        uint32_t* w32 = (uint32_t*)&Wlds[0][0];
        #pragma unroll
        for (int i = 0; i < 28; ++i) w32[tid + NTHR * i] = 0u;
        const float4* xg = (const float4*)(x + (size_t)bbase * T_STEPS);
        #pragma unroll
        for (int i = 0; i < 4; ++i) {
            const int gi = tid + NTHR * i;           // 0..1023
            *(float4*)&xs[gi >> 6][4 * (gi & 63)] = xg[gi];
        }
    }
    __syncthreads();
    // ---- fill extended matrix + zero state ----
    for (int i = tid; i < H2 * H2; i += NTHR) Wlds[i / H2][i % H2] = (f16)Whh2[i];
    for (int i = tid; i < H2 * H1; i += NTHR) Wlds[i / H1][H2 + i % H1] = (f16)Wih2[i];
    for (int i = tid; i < H2; i += NTHR)      Wlds[i][105] = (f16)(bih2[i] + bhh2[i]);
    if (tid < H1 * H1) Wlds[H2 + tid / H1][H2 + tid % H1] = (f16)Whh1[tid];
    if (tid < H1) {
        Wlds[H2 + tid][105] = (f16)(bih1[tid] + bhh1[tid]);
        Wlds[H2 + tid][106] = (f16)Wih1[tid];
    }
    {
        uint32_t* s32 = (uint32_t*)&st[0][0];
        #pragma unroll
        for (int i = 0; i < 8; ++i) s32[tid + NTHR * i] = 0u;
    }
    __syncthreads();
    // ---- initial state: h1_0 at k=100..104 (buf0), 1 at k=105 (BOTH bufs),
    //      x_1 at k=106 (buf0). Rows 107..127 stay zero forever. ----
    if (tid < NSTR) {
        const float x0 = xs[tid][0];
        #pragma unroll
        for (int c = 0; c < H1; ++c)
            st[0][sidx(H2 + c, tid)] = (f16)fast_tanh(Wih1[c] * x0 + bih1[c] + bhh1[c]);
        st[0][sidx(105, tid)] = (f16)1.0f;
        st[1][sidx(105, tid)] = (f16)1.0f;
        st[0][sidx(106, tid)] = (f16)xs[tid][1];
    }
    // ---- A fragments: wave w<3 -> tiles {2w, 2w+1}; wave 3 -> tile 6 ----
    const int mt0 = 2 * wid;
    half8 Af0[KT], Af1[KT];
    #pragma unroll
    for (int kt = 0; kt < KT; ++kt)
        Af0[kt] = *(const half8*)&Wlds[16 * mt0 + n][32 * kt + 8 * g];
    if (wid < 3) {
        #pragma unroll
        for (int kt = 0; kt < KT; ++kt)
            Af1[kt] = *(const half8*)&Wlds[16 * (mt0 + 1) + n][32 * kt + 8 * g];
    }
    __syncthreads();

    // read base: linear per lane; write slot for tile mt: rows 16mt+4g+{0..3}
    const int roff = 16 * lane;
    auto woffof = [&](int mt) {
        return (((4 * mt + g) >> 3) << 10) + (((2 * mt + (g >> 1)) & 3) << 8)
             + (n << 4) + ((g & 1) << 3);
    };
    const int woff0 = woffof(mt0);
    const int woff1 = woffof(mt0 + 1);
    char* const sp0 = (char*)&st[0][0];
    char* const sp1 = (char*)&st[1][0];
    uint32_t P0a = 0u, P1a = 0u, P0b = 0u, P1b = 0u;

    if (wid < 3) {
        // ---- heavy waves: 2 tiles, 4 reads feed 8 MFMAs ----
        auto step2 = [&](const char* rp, char* wp) {
            half8 Bf[KT];
            #pragma unroll
            for (int kt = 0; kt < KT; ++kt)
                Bf[kt] = *(const half8*)(rp + roff + 1024 * kt);
            floatx4 Da = {0.f,0.f,0.f,0.f}, Db = {0.f,0.f,0.f,0.f};
            floatx4 Dc = {0.f,0.f,0.f,0.f}, Dd = {0.f,0.f,0.f,0.f};
            Da = MFMA(Af0[0], Bf[0], Da);  Dc = MFMA(Af1[0], Bf[0], Dc);
            Db = MFMA(Af0[2], Bf[2], Db);  Dd = MFMA(Af1[2], Bf[2], Dd);
            Da = MFMA(Af0[1], Bf[1], Da);  Dc = MFMA(Af1[1], Bf[1], Dc);
            Db = MFMA(Af0[3], Bf[3], Db);  Dd = MFMA(Af1[3], Bf[3], Dd);
            const floatx4 D0 = Da + Db, D1 = Dc + Dd;
            uint2 w0, w1;
            w0.x = pkf16(fast_tanh(D0[0]), fast_tanh(D0[1]));
            w0.y = pkf16(fast_tanh(D0[2]), fast_tanh(D0[3]));
            w1.x = pkf16(fast_tanh(D1[0]), fast_tanh(D1[1]));
            w1.y = pkf16(fast_tanh(D1[2]), fast_tanh(D1[3]));
            *(uint2*)(wp + woff0) = w0;
            *(uint2*)(wp + woff1) = w1;
            __syncthreads();
        };
        #pragma unroll 1
        for (int t2 = 0; t2 < T_STEPS - 2; t2 += 2) {
            step2(sp0, sp1);
            step2(sp1, sp0);
        }
        step2(sp0, sp1);                   // t = 254: st0 -> st1
        // final step t = 255: compute only
        half8 Bf[KT];
        #pragma unroll
        for (int kt = 0; kt < KT; ++kt)
            Bf[kt] = *(const half8*)(sp1 + roff + 1024 * kt);
        floatx4 Da = {0.f,0.f,0.f,0.f}, Db = {0.f,0.f,0.f,0.f};
        floatx4 Dc = {0.f,0.f,0.f,0.f}, Dd = {0.f,0.f,0.f,0.f};
        Da = MFMA(Af0[0], Bf[0], Da);  Dc = MFMA(Af1[0], Bf[0], Dc);
        Db = MFMA(Af0[2], Bf[2], Db);  Dd = MFMA(Af1[2], Bf[2], Dd);
        Da = MFMA(Af0[1], Bf[1], Da);  Dc = MFMA(Af1[1], Bf[1], Dc);
        Db = MFMA(Af0[3], Bf[3], Db);  Dd = MFMA(Af1[3], Bf[3], Dd);
        const floatx4 D0 = Da + Db, D1 = Dc + Dd;
        P0a = pkf16(fast_tanh(D0[0]), fast_tanh(D0[1]));
        P1a = pkf16(fast_tanh(D0[2]), fast_tanh(D0[3]));
        P0b = pkf16(fast_tanh(D1[0]), fast_tanh(D1[1]));
        P1b = pkf16(fast_tanh(D1[2]), fast_tanh(D1[3]));
    } else {
        // ---- wave 3: tile 6 (rows 96..111) + x-injection on g3 lanes ----
        auto step1 = [&](const char* rp, char* wp, int t) {
            const int xi = (t + 2 < T_STEPS) ? (t + 2) : (T_STEPS - 1);
            const float xv = xs[n][xi];
            half8 Bf[KT];
            #pragma unroll
            for (int kt = 0; kt < KT; ++kt)
                Bf[kt] = *(const half8*)(rp + roff + 1024 * kt);
            floatx4 Da = {0.f,0.f,0.f,0.f}, Db = {0.f,0.f,0.f,0.f};
            Da = MFMA(Af0[0], Bf[0], Da);
            Db = MFMA(Af0[2], Bf[2], Db);
            Da = MFMA(Af0[1], Bf[1], Da);
            Db = MFMA(Af0[3], Bf[3], Db);
            const floatx4 D = Da + Db;
            if (g < 2) {                    // rows 96..103 all live
                uint2 w;
                w.x = pkf16(fast_tanh(D[0]), fast_tanh(D[1]));
                w.y = pkf16(fast_tanh(D[2]), fast_tanh(D[3]));
                *(uint2*)(wp + woff0) = w;
            } else if (g == 2) {            // rows 104..107: only 104 live
                *(f16*)(wp + 2 * (1664 + 8 * n)) = (f16)fast_tanh(D[0]);
            } else {                        // g == 3: rows dead -> inject x_{t+2}
                *(f16*)(wp + 2 * (1666 + 8 * n)) = (f16)xv;
            }
            __syncthreads();
        };
        #pragma unroll 1
        for (int t2 = 0; t2 < T_STEPS - 2; t2 += 2) {
            step1(sp0, sp1, t2);
            step1(sp1, sp0, t2 + 1);
        }
        step1(sp0, sp1, T_STEPS - 2);      // t = 254: st0 -> st1
        // final step t = 255: compute only
        half8 Bf[KT];
        #pragma unroll
        for (int kt = 0; kt < KT; ++kt)
            Bf[kt] = *(const half8*)(sp1 + roff + 1024 * kt);
        floatx4 Da = {0.f,0.f,0.f,0.f}, Db = {0.f,0.f,0.f,0.f};
        Da = MFMA(Af0[0], Bf[0], Da);
        Db = MFMA(Af0[2], Bf[2], Db);
        Da = MFMA(Af0[1], Bf[1], Da);
        Db = MFMA(Af0[3], Bf[3], Db);
        const floatx4 D = Da + Db;
        P0a = pkf16(fast_tanh(D[0]), fast_tanh(D[1]));
        P1a = pkf16(fast_tanh(D[2]), fast_tanh(D[3]));
    }

    // ---- epilogue: out[n] = relu(W3 . h2_255 + b3) ----
    float p = 0.0f;
    {
        const int mb0 = 16 * mt0 + 4 * g;
        if (mb0 < H2) {
            const float4 w3v = *(const float4*)(W3 + mb0);
            const f16x2 lo = __builtin_bit_cast(f16x2, P0a);
            const f16x2 hi = __builtin_bit_cast(f16x2, P1a);
            p += w3v.x * (float)lo.x + w3v.y * (float)lo.y
               + w3v.z * (float)hi.x + w3v.w * (float)hi.y;
        }
        if (wid < 3) {                      // tile mt0+1, rows always < 100
            const int mb1 = 16 * (mt0 + 1) + 4 * g;
            const float4 w3v = *(const float4*)(W3 + mb1);
            const f16x2 lo = __builtin_bit_cast(f16x2, P0b);
            const f16x2 hi = __builtin_bit_cast(f16x2, P1b);
            p += w3v.x * (float)lo.x + w3v.y * (float)lo.y
               + w3v.z * (float)hi.x + w3v.w * (float)hi.y;
        }
    }
    p += __shfl_xor(p, 16);
    p += __shfl_xor(p, 32);
    if (lane < NSTR) pp[wid][n] = p;
    __syncthreads();
    if (tid < NSTR) {
        float s = b3[0];
        #pragma unroll
        for (int w = 0; w < NW; ++w) s += pp[w][tid];
        out[bbase + tid] = fmaxf(s, 0.0f);
    }
}

extern "C" void kernel_launch(void* const* d_in, const int* in_sizes, int n_in,
                              void* d_out, int out_size, void* d_ws, size_t ws_size,
                              hipStream_t stream) {
    const float* x    = (const float*)d_in[0];
    const float* Wih1 = (const float*)d_in[1];
    const float* Whh1 = (const float*)d_in[2];
    const float* bih1 = (const float*)d_in[3];
    const float* bhh1 = (const float*)d_in[4];
    const float* Wih2 = (const float*)d_in[5];
    const float* Whh2 = (const float*)d_in[6];
    const float* bih2 = (const float*)d_in[7];
    const float* bhh2 = (const float*)d_in[8];
    const float* W3   = (const float*)d_in[9];
    const float* b3   = (const float*)d_in[10];
    float* out = (float*)d_out;

    const int B = in_sizes[0] / T_STEPS;   // 4096
    rnn_mfma4w<<<B / NSTR, NTHR, 0, stream>>>(x, Wih1, Whh1, bih1, bhh1,
                                              Wih2, Whh2, bih2, bhh2, W3, b3, out);
}